// Round 4
// baseline (2151.269 us; speedup 1.0000x reference)
//
#include <hip/hip_runtime.h>
#include <hip/hip_fp16.h>

typedef _Float16 f16;
typedef _Float16 f16x2 __attribute__((ext_vector_type(2)));
typedef _Float16 f16x4 __attribute__((ext_vector_type(4)));
typedef _Float16 f16x8 __attribute__((ext_vector_type(8)));
typedef float    f32x4 __attribute__((ext_vector_type(4)));

// Problem constants: B=64, S=32, P=49, F=2048, E=512, H=512, V=32000

// ---------------- f32 -> f16 convert (vectorized) ----------------
__global__ void k_cvt(const float* __restrict__ in, f16* __restrict__ out, long n4) {
  long i = (long)blockIdx.x * blockDim.x + threadIdx.x;
  long stride = (long)gridDim.x * blockDim.x;
  for (; i < n4; i += stride) {
    float4 v = ((const float4*)in)[i];
    f16x4 o;
    o.x = (f16)v.x; o.y = (f16)v.y; o.z = (f16)v.z; o.w = (f16)v.w;
    ((f16x4*)out)[i] = o;
  }
}

// ---------------- embedding gather -> f16 A matrix (n = b*32+s) ----------------
__global__ void k_embed(const int* __restrict__ caps, const float* __restrict__ table,
                        f16* __restrict__ out) {
  int n = blockIdx.x;                 // 0..2047
  int tok = caps[n];
  const float* src = table + (long)tok * 512;
  f16* dst = out + (long)n * 512;
  for (int e = threadIdx.x; e < 512; e += 256) dst[e] = (f16)src[e];
}

// ---------------- mean of features over P (from f16 feat) -> f16 [64,2048] ----------------
__global__ __launch_bounds__(256) void k_mean(const f16* __restrict__ feat_h,
                                              f16* __restrict__ mean_h) {
  int b = blockIdx.x;
  int e4 = blockIdx.y * 256 + threadIdx.x;      // f16x4 index within row: 0..511
  const f16x4* src = (const f16x4*)(feat_h + (long)b * 49 * 2048) + e4;
  float s0 = 0.f, s1 = 0.f, s2 = 0.f, s3 = 0.f;
#pragma unroll 7
  for (int p = 0; p < 49; ++p) {
    f16x4 v = src[p * 512];
    s0 += (float)v.x; s1 += (float)v.y; s2 += (float)v.z; s3 += (float)v.w;
  }
  const float inv = 1.f / 49.f;
  f16x4 o; o.x = (f16)(s0 * inv); o.y = (f16)(s1 * inv); o.z = (f16)(s2 * inv); o.w = (f16)(s3 * inv);
  ((f16x4*)(mean_h + (long)b * 2048))[e4] = o;
}

// ---------------- split h0/c0 GEMM result, add biases ----------------
__global__ __launch_bounds__(512) void k_h0split(const float* __restrict__ Rh0,
                                                 const float* __restrict__ bh,
                                                 const float* __restrict__ bc,
                                                 f16* __restrict__ h16,
                                                 float* __restrict__ c_state) {
  int b = blockIdx.x, j = threadIdx.x;
  h16[(long)b * 512 + j] = (f16)(Rh0[(long)b * 1024 + j] + bh[j]);
  c_state[(long)b * 512 + j] = Rh0[(long)b * 1024 + 512 + j] + bc[j];
}

// ---------------- generic f16 MFMA GEMM: C[M,N] = A[M,K] @ W[N,K]^T + bias ----------------
// 1-D grid, M-fastest mapping: consecutive blocks share the same W stripe (L2/L3 reuse).
// mode 0: f32 out @ ldc ; mode 1: f16 out @ ldc ; mode 2: f16 out g-interleaved (featW4)
__global__ __launch_bounds__(256) void k_gemm(const f16* __restrict__ A, long lda,
                                              const f16* __restrict__ Bw, long ldb,
                                              const float* __restrict__ bias1,
                                              const float* __restrict__ bias2,
                                              void* __restrict__ Cout, long ldc,
                                              int K, int mode, int n_mtiles) {
  __shared__ f16 As[64][40];   // +8 pad: bank-conflict-friendly b128 reads
  __shared__ f16 Bs[64][40];
  const int tid = threadIdx.x;
  const int lane = tid & 63, wave = tid >> 6;
  const int bid = blockIdx.x;
  const long m0 = (long)(bid % n_mtiles) * 64, n0 = (long)(bid / n_mtiles) * 64;
  const int lr = tid >> 2, lc = (tid & 3) * 8;
  const int wr = (wave >> 1) * 32, wc = (wave & 1) * 32;
  f32x4 acc[2][2] = {};
  const f16* Ap = A + (m0 + lr) * lda + lc;
  const f16* Bp = Bw + (n0 + lr) * ldb + lc;
  for (int k0 = 0; k0 < K; k0 += 32) {
    uint4 av = *(const uint4*)(Ap + k0);
    uint4 bv = *(const uint4*)(Bp + k0);
    __syncthreads();
    *(uint4*)&As[lr][lc] = av;
    *(uint4*)&Bs[lr][lc] = bv;
    __syncthreads();
#pragma unroll
    for (int mi = 0; mi < 2; ++mi) {
      f16x8 af = *(const f16x8*)&As[wr + mi * 16 + (lane & 15)][(lane >> 4) * 8];
#pragma unroll
      for (int ni = 0; ni < 2; ++ni) {
        f16x8 bf = *(const f16x8*)&Bs[wc + ni * 16 + (lane & 15)][(lane >> 4) * 8];
        acc[mi][ni] = __builtin_amdgcn_mfma_f32_16x16x32_f16(af, bf, acc[mi][ni], 0, 0, 0);
      }
    }
  }
#pragma unroll
  for (int mi = 0; mi < 2; ++mi)
#pragma unroll
    for (int ni = 0; ni < 2; ++ni) {
      int row_b = wr + mi * 16 + (lane >> 4) * 4;
      long gcol = n0 + wc + ni * 16 + (lane & 15);
      float badd = (bias1 ? bias1[gcol] : 0.f) + (bias2 ? bias2[gcol] : 0.f);
#pragma unroll
      for (int r = 0; r < 4; ++r) {
        long grow = m0 + row_b + r;
        float v = acc[mi][ni][r] + badd;
        if (mode == 0)      ((float*)Cout)[grow * ldc + gcol] = v;
        else if (mode == 1) ((f16*)Cout)[grow * ldc + gcol] = (f16)v;
        else                ((f16*)Cout)[grow * 2048 + ((gcol & 511) << 2) + (gcol >> 9)] = (f16)v;
      }
    }
}

// ---------------- device-scope grid barrier (monotonic counter) ----------------
static __device__ __forceinline__ void gbar(unsigned* bar, unsigned target) {
  __threadfence();            // release all prior writes device-wide
  __syncthreads();
  if (threadIdx.x == 0) {
    __hip_atomic_fetch_add(bar, 1u, __ATOMIC_RELEASE, __HIP_MEMORY_SCOPE_AGENT);
    while (__hip_atomic_load(bar, __ATOMIC_ACQUIRE, __HIP_MEMORY_SCOPE_AGENT) < target) {
      __builtin_amdgcn_s_sleep(2);
    }
  }
  __syncthreads();
  __threadfence();            // acquire: invalidate stale cache lines
}

// ---------------- fused recurrence: 64 persistent blocks, 32 steps, 2 barriers/step --------
// Blocks 0..39: GEMM phase R[64,2560] = h @ [W_hh;U_a]^T (weight stripe persistent in LDS).
// Blocks 0..63: step phase for batch b = blockIdx.x.
__global__ __launch_bounds__(512, 1) void k_loop(
    const f16* __restrict__ Wcat, const float* __restrict__ b_Ua,
    const f16* __restrict__ att1, const float* __restrict__ va,
    const f16* __restrict__ featW4, const float* __restrict__ gates_x,
    const float* __restrict__ c_state, f16* __restrict__ h16,
    f16* __restrict__ Hbuf, float* __restrict__ attw_out,
    float* __restrict__ R, unsigned* __restrict__ bar) {
  __shared__ f16 Bs[64][520];   // weight stripe, persistent (pad: 1040B rows, 16B-aligned)
  __shared__ f16 As[64][520];   // h staging, reloaded per step
  __shared__ float att2[512];
  __shared__ float sc[64];
  __shared__ float wl[49];
  const int blk = blockIdx.x, tid = threadIdx.x;
  const int lane = tid & 63, wave = tid >> 6;
  const int b = blk;
  const int n0 = blk * 64;

  // persistent per-block state
  float c = c_state[(long)b * 512 + tid];     // c lives in a register for all 32 steps
  const float bua_r = b_Ua[tid];
  float va_r[8];
#pragma unroll
  for (int kk = 0; kk < 8; ++kk) va_r[kk] = va[lane + kk * 64];

  // prologue: blocks 0..39 load their Wcat stripe (rows n0..n0+63) into LDS, once
  if (blk < 40) {
#pragma unroll
    for (int i = 0; i < 8; ++i) {
      int u4 = i * 512 + tid;
      int row = u4 >> 6, col = (u4 & 63) * 8;
      *(uint4*)&Bs[row][col] = *(const uint4*)(Wcat + ((long)(n0 + row) << 9) + col);
    }
  }
  // no barrier needed: Bs is block-local

  unsigned bs = 0;
  for (int t = 0; t < 32; ++t) {
    const long n = (long)b * 32 + t;
    // ---------- GEMM phase: R = h @ Wcat^T ----------
    if (blk < 40) {
      __syncthreads();          // As reads from step t-1 done (also covered by gbar)
#pragma unroll
      for (int i = 0; i < 8; ++i) {
        int u4 = i * 512 + tid;
        int row = u4 >> 6, col = (u4 & 63) * 8;
        *(uint4*)&As[row][col] = *(const uint4*)(h16 + ((long)row << 9) + col);
      }
      __syncthreads();
      const int wr = (wave >> 2) * 32, wc = (wave & 3) * 16;
      f32x4 acc0 = {}, acc1 = {};
#pragma unroll
      for (int k0 = 0; k0 < 16; ++k0) {
        int kc = k0 * 32 + (lane >> 4) * 8;
        f16x8 b0 = *(const f16x8*)&Bs[wc + (lane & 15)][kc];
        f16x8 a0 = *(const f16x8*)&As[wr + (lane & 15)][kc];
        f16x8 a1 = *(const f16x8*)&As[wr + 16 + (lane & 15)][kc];
        acc0 = __builtin_amdgcn_mfma_f32_16x16x32_f16(a0, b0, acc0, 0, 0, 0);
        acc1 = __builtin_amdgcn_mfma_f32_16x16x32_f16(a1, b0, acc1, 0, 0, 0);
      }
      int cc = n0 + wc + (lane & 15);
      int r0 = wr + (lane >> 4) * 4;
#pragma unroll
      for (int r = 0; r < 4; ++r) {
        R[(long)(r0 + r) * 2560 + cc] = acc0[r];
        R[(long)(r0 + 16 + r) * 2560 + cc] = acc1[r];
      }
    }
    ++bs; gbar(bar, bs * 64u);   // R ready

    // ---------- step phase: attention + softmax + ctx + LSTM ----------
    const float* Rb = R + (long)b * 2560;
    att2[tid] = Rb[2048 + tid] + bua_r;
    __syncthreads();

    for (int p = wave; p < 49; p += 8) {
      const f16* arow = att1 + ((long)b * 49 + p) * 512;
      float s = 0.f;
#pragma unroll
      for (int kk = 0; kk < 8; ++kk) {
        int k = lane + kk * 64;
        float x = (float)arow[k] + att2[k];
        float e = __expf(2.f * x);
        float th = 1.f - 2.f / (e + 1.f);
        s += va_r[kk] * th;
      }
#pragma unroll
      for (int off = 32; off; off >>= 1) s += __shfl_xor(s, off);
      if (lane == 0) sc[p] = s;
    }
    __syncthreads();

    if (wave == 0) {
      float s = (lane < 49) ? sc[lane] : -1e30f;
      float m = s;
#pragma unroll
      for (int off = 32; off; off >>= 1) m = fmaxf(m, __shfl_xor(m, off));
      float e = (lane < 49) ? __expf(s - m) : 0.f;
      float sum = e;
#pragma unroll
      for (int off = 32; off; off >>= 1) sum += __shfl_xor(sum, off);
      float wv = e / sum;
      if (lane < 49) { wl[lane] = wv; attw_out[n * 49 + lane] = wv; }
    }
    __syncthreads();

    const float* gx = gates_x + n * 2048;
    float g0 = gx[tid] + Rb[tid];
    float g1 = gx[512 + tid] + Rb[512 + tid];
    float g2 = gx[1024 + tid] + Rb[1024 + tid];
    float g3 = gx[1536 + tid] + Rb[1536 + tid];
    const f16* fwbase = featW4 + (long)b * 49 * 2048 + tid * 4;
#pragma unroll 7
    for (int p = 0; p < 49; ++p) {
      float wp = wl[p];
      uint2 u = *(const uint2*)(fwbase + (long)p * 2048);
      f16x2 aa = __builtin_bit_cast(f16x2, u.x);
      f16x2 bb = __builtin_bit_cast(f16x2, u.y);
      g0 += wp * (float)aa.x; g1 += wp * (float)aa.y;
      g2 += wp * (float)bb.x; g3 += wp * (float)bb.y;
    }
    float iv = 1.f / (1.f + __expf(-g0));
    float fv = 1.f / (1.f + __expf(-g1));
    float e2 = __expf(2.f * g2); float gv = 1.f - 2.f / (e2 + 1.f);
    float ov = 1.f / (1.f + __expf(-g3));
    c = fv * c + iv * gv;
    float e3 = __expf(2.f * c); float tc = 1.f - 2.f / (e3 + 1.f);
    float hn = ov * tc;
    h16[(long)b * 512 + tid] = (f16)hn;
    Hbuf[n * 512 + tid] = (f16)hn;

    ++bs; gbar(bar, bs * 64u);   // h16 ready for next step
  }
}

extern "C" void kernel_launch(void* const* d_in, const int* in_sizes, int n_in,
                              void* d_out, int out_size, void* d_ws, size_t ws_size,
                              hipStream_t stream) {
  const int*   caps = (const int*)d_in[0];
  const float* feat = (const float*)d_in[1];
  const float* etab = (const float*)d_in[2];
  const float* W_a  = (const float*)d_in[3];
  const float* b_Wa = (const float*)d_in[4];
  const float* U_a  = (const float*)d_in[5];
  const float* b_Ua = (const float*)d_in[6];
  const float* v_a  = (const float*)d_in[7];
  /* d_in[8] b_va: softmax-invariant, unused */
  const float* W_ih = (const float*)d_in[9];
  const float* b_ih = (const float*)d_in[10];
  const float* W_hh = (const float*)d_in[11];
  const float* b_hh = (const float*)d_in[12];
  const float* fc_W = (const float*)d_in[13];
  const float* fc_b = (const float*)d_in[14];
  const float* Wh   = (const float*)d_in[15];
  const float* bh   = (const float*)d_in[16];
  const float* Wc   = (const float*)d_in[17];
  const float* bc   = (const float*)d_in[18];

  char* ws = (char*)d_ws;
  size_t off = 0;
  auto alloc = [&](size_t bytes) { void* p = ws + off; off += (bytes + 255) & ~(size_t)255; return p; };
  f16* feat_h  = (f16*)alloc(6422528ull * 2);   // B*P*F
  f16* W_a_h   = (f16*)alloc(1048576ull * 2);   // H*F
  f16* W_ih_h  = (f16*)alloc(5242880ull * 2);   // 4H*(E+F)
  f16* fc_W_h  = (f16*)alloc(16384000ull * 2);  // V*H
  f16* Aemb    = (f16*)alloc(1048576ull * 2);   // B*S*E
  f16* Wcat_h  = (f16*)alloc(1310720ull * 2);   // [W_hh;U_a] = [2560,512] f16
  f16* Whc_h   = (f16*)alloc(2097152ull * 2);   // [Wh;Wc] = [1024,2048] f16
  f16* mean_h  = (f16*)alloc(131072ull * 2);    // [64,2048] mean features f16
  f16* att1_h  = (f16*)alloc(1605632ull * 2);   // B*P*H
  f16* featW4  = (f16*)alloc(6422528ull * 2);   // B*P*4H interleaved
  float* gates_x = (float*)alloc(4194304ull * 4); // B*S*4H
  float* R     = (float*)alloc(163840ull * 4);  // [64,2560] per-step GEMM out (also h0/c0 out)
  f16* h16     = (f16*)alloc(32768ull * 2);     // [64,512] h state
  float* c_state = (float*)alloc(32768ull * 4); // [64,512] c state
  f16* Hbuf    = (f16*)alloc(1048576ull * 2);   // B*S*H
  unsigned* bar = (unsigned*)alloc(256);        // grid-barrier counter
  (void)ws_size; (void)in_sizes; (void)n_in; (void)out_size;

  float* out_logits = (float*)d_out;
  float* out_attw   = out_logits + 65536000ull;

  // Phase A: converts / packs / precompute
  hipMemsetAsync(bar, 0, 256, stream);
  k_cvt<<<2048, 256, 0, stream>>>(feat, feat_h, 6422528 / 4);
  k_cvt<<<1024, 256, 0, stream>>>(W_a, W_a_h, 1048576 / 4);
  k_cvt<<<2048, 256, 0, stream>>>(W_ih, W_ih_h, 5242880 / 4);
  k_cvt<<<4096, 256, 0, stream>>>(fc_W, fc_W_h, 16384000 / 4);
  k_cvt<<<1024, 256, 0, stream>>>(W_hh, Wcat_h, 1048576 / 4);              // rows 0..2047
  k_cvt<<<256, 256, 0, stream>>>(U_a, Wcat_h + 2048ull * 512, 262144 / 4); // rows 2048..2559
  k_cvt<<<512, 256, 0, stream>>>(Wh, Whc_h, 1048576 / 4);                  // rows 0..511
  k_cvt<<<512, 256, 0, stream>>>(Wc, Whc_h + 1048576ull, 1048576 / 4);     // rows 512..1023
  k_embed<<<2048, 256, 0, stream>>>(caps, etab, Aemb);
  k_mean<<<dim3(64, 2), 256, 0, stream>>>(feat_h, mean_h);

  dim3 blk(256);
  // h0/c0: [64,1024] = mean_h @ [Wh;Wc]^T  K=2048 -> f32 (biases added in split)
  k_gemm<<<16, blk, 0, stream>>>(mean_h, 2048, Whc_h, 2048,
                                 nullptr, nullptr, R, 1024, 2048, 0, 1);
  k_h0split<<<64, 512, 0, stream>>>(R, bh, bc, h16, c_state);

  // att1 = features @ W_a^T + b_Wa         [3136,512]  K=2048 -> f16   (49 m-tiles, 8 n-tiles)
  k_gemm<<<49 * 8, blk, 0, stream>>>(feat_h, 2048, W_a_h, 2048,
                                     b_Wa, nullptr, att1_h, 512, 2048, 1, 49);
  // featW = features @ W_ih[:,E:]^T        [3136,2048] K=2048 -> f16 g-interleaved (49 x 32)
  k_gemm<<<49 * 32, blk, 0, stream>>>(feat_h, 2048, W_ih_h + 512, 2560,
                                      nullptr, nullptr, featW4, 0, 2048, 2, 49);
  // gates_x = embed @ W_ih[:,:E]^T + b_ih + b_hh   [2048,2048] K=512 -> f32 (32 x 32)
  k_gemm<<<32 * 32, blk, 0, stream>>>(Aemb, 512, W_ih_h, 2560,
                                      b_ih, b_hh, gates_x, 2048, 512, 0, 32);

  // Phase B: fused sequential recurrence (single persistent kernel, internal grid barriers)
  k_loop<<<64, 512, 0, stream>>>(Wcat_h, b_Ua, att1_h, v_a, featW4, gates_x,
                                 c_state, h16, Hbuf, out_attw, R, bar);

  // Phase C: logits = H @ fc_W^T + fc_b    [2048,32000] K=512 -> f32 (32 m-tiles, 500 n-tiles)
  k_gemm<<<32 * 500, blk, 0, stream>>>(Hbuf, 512, fc_W_h, 512,
                                       fc_b, nullptr, out_logits, 32000, 512, 0, 32);
}

// Round 5
// 1043.289 us; speedup vs baseline: 2.0620x; 2.0620x over previous
//
#include <hip/hip_runtime.h>
#include <hip/hip_fp16.h>

typedef _Float16 f16;
typedef _Float16 f16x2 __attribute__((ext_vector_type(2)));
typedef _Float16 f16x4 __attribute__((ext_vector_type(4)));
typedef _Float16 f16x8 __attribute__((ext_vector_type(8)));
typedef float    f32x4 __attribute__((ext_vector_type(4)));

// Problem constants: B=64, S=32, P=49, F=2048, E=512, H=512, V=32000

// ---------------- f32 -> f16 convert (vectorized) ----------------
__global__ void k_cvt(const float* __restrict__ in, f16* __restrict__ out, long n4) {
  long i = (long)blockIdx.x * blockDim.x + threadIdx.x;
  long stride = (long)gridDim.x * blockDim.x;
  for (; i < n4; i += stride) {
    float4 v = ((const float4*)in)[i];
    f16x4 o;
    o.x = (f16)v.x; o.y = (f16)v.y; o.z = (f16)v.z; o.w = (f16)v.w;
    ((f16x4*)out)[i] = o;
  }
}

// ---------------- embedding gather -> f16 A matrix (n = b*32+s) ----------------
__global__ void k_embed(const int* __restrict__ caps, const float* __restrict__ table,
                        f16* __restrict__ out) {
  int n = blockIdx.x;                 // 0..2047
  int tok = caps[n];
  const float* src = table + (long)tok * 512;
  f16* dst = out + (long)n * 512;
  for (int e = threadIdx.x; e < 512; e += 256) dst[e] = (f16)src[e];
}

// ---------------- mean of features over P (from f16 feat) -> f16 [64,2048] ----------------
__global__ __launch_bounds__(256) void k_mean(const f16* __restrict__ feat_h,
                                              f16* __restrict__ mean_h) {
  int b = blockIdx.x;
  int e4 = blockIdx.y * 256 + threadIdx.x;      // f16x4 index within row: 0..511
  const f16x4* src = (const f16x4*)(feat_h + (long)b * 49 * 2048) + e4;
  float s0 = 0.f, s1 = 0.f, s2 = 0.f, s3 = 0.f;
#pragma unroll 7
  for (int p = 0; p < 49; ++p) {
    f16x4 v = src[p * 512];
    s0 += (float)v.x; s1 += (float)v.y; s2 += (float)v.z; s3 += (float)v.w;
  }
  const float inv = 1.f / 49.f;
  f16x4 o; o.x = (f16)(s0 * inv); o.y = (f16)(s1 * inv); o.z = (f16)(s2 * inv); o.w = (f16)(s3 * inv);
  ((f16x4*)(mean_h + (long)b * 2048))[e4] = o;
}

// ---------------- split h0/c0 GEMM result, add biases ----------------
__global__ __launch_bounds__(512) void k_h0split(const float* __restrict__ Rh0,
                                                 const float* __restrict__ bh,
                                                 const float* __restrict__ bc,
                                                 f16* __restrict__ h16,
                                                 float* __restrict__ c_state) {
  int b = blockIdx.x, j = threadIdx.x;
  h16[(long)b * 512 + j] = (f16)(Rh0[(long)b * 1024 + j] + bh[j]);
  c_state[(long)b * 512 + j] = Rh0[(long)b * 1024 + 512 + j] + bc[j];
}

// ---------------- generic f16 MFMA GEMM (64x64 tile): C = A @ W^T + bias ----------------
// 1-D grid, M-fastest mapping. mode 0: f32 out; mode 1: f16 out; mode 2: f16 g-interleaved
__global__ __launch_bounds__(256) void k_gemm(const f16* __restrict__ A, long lda,
                                              const f16* __restrict__ Bw, long ldb,
                                              const float* __restrict__ bias1,
                                              const float* __restrict__ bias2,
                                              void* __restrict__ Cout, long ldc,
                                              int K, int mode, int n_mtiles) {
  __shared__ f16 As[64][40];
  __shared__ f16 Bs[64][40];
  const int tid = threadIdx.x;
  const int lane = tid & 63, wave = tid >> 6;
  const int bid = blockIdx.x;
  const long m0 = (long)(bid % n_mtiles) * 64, n0 = (long)(bid / n_mtiles) * 64;
  const int lr = tid >> 2, lc = (tid & 3) * 8;
  const int wr = (wave >> 1) * 32, wc = (wave & 1) * 32;
  f32x4 acc[2][2] = {};
  const f16* Ap = A + (m0 + lr) * lda + lc;
  const f16* Bp = Bw + (n0 + lr) * ldb + lc;
  for (int k0 = 0; k0 < K; k0 += 32) {
    uint4 av = *(const uint4*)(Ap + k0);
    uint4 bv = *(const uint4*)(Bp + k0);
    __syncthreads();
    *(uint4*)&As[lr][lc] = av;
    *(uint4*)&Bs[lr][lc] = bv;
    __syncthreads();
#pragma unroll
    for (int mi = 0; mi < 2; ++mi) {
      f16x8 af = *(const f16x8*)&As[wr + mi * 16 + (lane & 15)][(lane >> 4) * 8];
#pragma unroll
      for (int ni = 0; ni < 2; ++ni) {
        f16x8 bf = *(const f16x8*)&Bs[wc + ni * 16 + (lane & 15)][(lane >> 4) * 8];
        acc[mi][ni] = __builtin_amdgcn_mfma_f32_16x16x32_f16(af, bf, acc[mi][ni], 0, 0, 0);
      }
    }
  }
#pragma unroll
  for (int mi = 0; mi < 2; ++mi)
#pragma unroll
    for (int ni = 0; ni < 2; ++ni) {
      int row_b = wr + mi * 16 + (lane >> 4) * 4;
      long gcol = n0 + wc + ni * 16 + (lane & 15);
      float badd = (bias1 ? bias1[gcol] : 0.f) + (bias2 ? bias2[gcol] : 0.f);
#pragma unroll
      for (int r = 0; r < 4; ++r) {
        long grow = m0 + row_b + r;
        float v = acc[mi][ni][r] + badd;
        if (mode == 0)      ((float*)Cout)[grow * ldc + gcol] = v;
        else if (mode == 1) ((f16*)Cout)[grow * ldc + gcol] = (f16)v;
        else                ((f16*)Cout)[grow * 2048 + ((gcol & 511) << 2) + (gcol >> 9)] = (f16)v;
      }
    }
}

// ---------------- 128x128-tile f16 MFMA GEMM: C[M,N] = A[M,K] @ W[N,K]^T + bias (f32 out) ---
// 512 threads / 8 waves (4 m x 2 n). 1-D grid, M-fastest.
__global__ __launch_bounds__(512) void k_gemm128(const f16* __restrict__ A, long lda,
                                                 const f16* __restrict__ Bw, long ldb,
                                                 const float* __restrict__ bias1,
                                                 const float* __restrict__ bias2,
                                                 float* __restrict__ Cout, long ldc,
                                                 int K, int n_mtiles) {
  __shared__ f16 As[128][40];
  __shared__ f16 Bs[128][40];
  const int tid = threadIdx.x;
  const int lane = tid & 63, wave = tid >> 6;
  const int wm = wave & 3, wn = wave >> 2;      // wave -> 32-row m strip, 64-col n strip
  const int bid = blockIdx.x;
  const long m0 = (long)(bid % n_mtiles) * 128, n0 = (long)(bid / n_mtiles) * 128;
  const int lr = tid >> 2, lc = (tid & 3) * 8;
  f32x4 acc[2][4] = {};
  const f16* Ap = A + (m0 + lr) * lda + lc;
  const f16* Bp = Bw + (n0 + lr) * ldb + lc;
  for (int k0 = 0; k0 < K; k0 += 32) {
    uint4 av = *(const uint4*)(Ap + k0);
    uint4 bv = *(const uint4*)(Bp + k0);
    __syncthreads();
    *(uint4*)&As[lr][lc] = av;
    *(uint4*)&Bs[lr][lc] = bv;
    __syncthreads();
#pragma unroll
    for (int mi = 0; mi < 2; ++mi) {
      f16x8 af = *(const f16x8*)&As[wm * 32 + mi * 16 + (lane & 15)][(lane >> 4) * 8];
#pragma unroll
      for (int ni = 0; ni < 4; ++ni) {
        f16x8 bf = *(const f16x8*)&Bs[wn * 64 + ni * 16 + (lane & 15)][(lane >> 4) * 8];
        acc[mi][ni] = __builtin_amdgcn_mfma_f32_16x16x32_f16(af, bf, acc[mi][ni], 0, 0, 0);
      }
    }
  }
#pragma unroll
  for (int mi = 0; mi < 2; ++mi)
#pragma unroll
    for (int ni = 0; ni < 4; ++ni) {
      int row_b = wm * 32 + mi * 16 + (lane >> 4) * 4;
      long gcol = n0 + wn * 64 + ni * 16 + (lane & 15);
      float badd = (bias1 ? bias1[gcol] : 0.f) + (bias2 ? bias2[gcol] : 0.f);
#pragma unroll
      for (int r = 0; r < 4; ++r) {
        long grow = m0 + row_b + r;
        Cout[grow * ldc + gcol] = acc[mi][ni][r] + badd;
      }
    }
}

// ---------------- per-step R = h @ [W_hh;U_a]^T — register-direct MFMA, no LDS/barriers ----
// grid 40 x 256: block covers 64 cols (n0); wave w covers m-rows w*16..w*16+15.
__global__ __launch_bounds__(256) void k_rgemm(const f16* __restrict__ h16,
                                               const f16* __restrict__ Wcat,
                                               float* __restrict__ R) {
  const int tid = threadIdx.x, lane = tid & 63, wave = tid >> 6;
  const int n0 = blockIdx.x * 64;
  const int l15 = lane & 15;
  const int koff = (lane >> 4) * 8;
  f32x4 acc[4] = {};
  const f16* Ap = h16 + ((long)(wave * 16 + l15) << 9) + koff;   // h row for A-frag
#pragma unroll
  for (int k0 = 0; k0 < 16; ++k0) {
    f16x8 af = *(const f16x8*)(Ap + k0 * 32);
#pragma unroll
    for (int ni = 0; ni < 4; ++ni) {
      f16x8 bf = *(const f16x8*)(Wcat + ((long)(n0 + ni * 16 + l15) << 9) + koff + k0 * 32);
      acc[ni] = __builtin_amdgcn_mfma_f32_16x16x32_f16(af, bf, acc[ni], 0, 0, 0);
    }
  }
  const int r0 = wave * 16 + (lane >> 4) * 4;
#pragma unroll
  for (int ni = 0; ni < 4; ++ni) {
    int col = n0 + ni * 16 + l15;
#pragma unroll
    for (int r = 0; r < 4; ++r)
      R[(long)(r0 + r) * 2560 + col] = acc[ni][r];
  }
}

// ---------------- per-step: attention + softmax + ctx + LSTM pointwise ----------------
// R[b, 0:2048] = h @ W_hh^T ; R[b, 2048:2560] = h @ U_a^T  (both raw)
__global__ __launch_bounds__(512) void k_step(const float* __restrict__ R,
                                              const float* __restrict__ b_Ua,
                                              const f16* __restrict__ att1,
                                              const float* __restrict__ va,
                                              const f16* __restrict__ featW4,
                                              const float* __restrict__ gates_x,
                                              float* __restrict__ c_state,
                                              f16* __restrict__ h16,
                                              f16* __restrict__ Hbuf,
                                              float* __restrict__ attw_out,
                                              int t) {
  __shared__ float att2[512];
  __shared__ float sc[64];
  __shared__ float wl[49];
  const int b = blockIdx.x, tid = threadIdx.x;
  const int lane = tid & 63, wave = tid >> 6;
  const long n = (long)b * 32 + t;
  const float* Rb = R + (long)b * 2560;
  const float* gx = gates_x + n * 2048;

  // issue gate inputs early — in flight during the attention phase
  float g0 = gx[tid] + Rb[tid];
  float g1 = gx[512 + tid] + Rb[512 + tid];
  float g2 = gx[1024 + tid] + Rb[1024 + tid];
  float g3 = gx[1536 + tid] + Rb[1536 + tid];
  float c = c_state[(long)b * 512 + tid];

  att2[tid] = Rb[2048 + tid] + b_Ua[tid];
  __syncthreads();

  // scores: wave w handles p = w, w+8, ...
  for (int p = wave; p < 49; p += 8) {
    const f16* arow = att1 + ((long)b * 49 + p) * 512;
    float s = 0.f;
#pragma unroll
    for (int kk = 0; kk < 8; ++kk) {
      int k = lane + kk * 64;
      float x = (float)arow[k] + att2[k];
      float e = __expf(2.f * x);
      float th = 1.f - 2.f / (e + 1.f);
      s += va[k] * th;
    }
#pragma unroll
    for (int off = 32; off; off >>= 1) s += __shfl_xor(s, off);
    if (lane == 0) sc[p] = s;
  }
  __syncthreads();

  // softmax over P=49 by wave 0 (b_va is a constant shift -> softmax-invariant)
  if (wave == 0) {
    float s = (lane < 49) ? sc[lane] : -1e30f;
    float m = s;
#pragma unroll
    for (int off = 32; off; off >>= 1) m = fmaxf(m, __shfl_xor(m, off));
    float e = (lane < 49) ? __expf(s - m) : 0.f;
    float sum = e;
#pragma unroll
    for (int off = 32; off; off >>= 1) sum += __shfl_xor(sum, off);
    float wv = e / sum;
    if (lane < 49) { wl[lane] = wv; attw_out[n * 49 + lane] = wv; }
  }
  __syncthreads();

  // context: sum_p w[p] * featW[b,p,col] for the 4 gate cols (fully unrolled for MLP)
  const f16* fwbase = featW4 + (long)b * 49 * 2048 + tid * 4;
#pragma unroll
  for (int p = 0; p < 49; ++p) {
    float wp = wl[p];
    uint2 u = *(const uint2*)(fwbase + (long)p * 2048);
    f16x2 aa = __builtin_bit_cast(f16x2, u.x);
    f16x2 bb = __builtin_bit_cast(f16x2, u.y);
    g0 += wp * (float)aa.x; g1 += wp * (float)aa.y;
    g2 += wp * (float)bb.x; g3 += wp * (float)bb.y;
  }
  // LSTM pointwise
  float iv = 1.f / (1.f + __expf(-g0));
  float fv = 1.f / (1.f + __expf(-g1));
  float e2 = __expf(2.f * g2); float gv = 1.f - 2.f / (e2 + 1.f);
  float ov = 1.f / (1.f + __expf(-g3));
  c = fv * c + iv * gv;
  float e3 = __expf(2.f * c); float tc = 1.f - 2.f / (e3 + 1.f);
  float hn = ov * tc;
  c_state[(long)b * 512 + tid] = c;
  h16[(long)b * 512 + tid] = (f16)hn;
  Hbuf[n * 512 + tid] = (f16)hn;
}

extern "C" void kernel_launch(void* const* d_in, const int* in_sizes, int n_in,
                              void* d_out, int out_size, void* d_ws, size_t ws_size,
                              hipStream_t stream) {
  const int*   caps = (const int*)d_in[0];
  const float* feat = (const float*)d_in[1];
  const float* etab = (const float*)d_in[2];
  const float* W_a  = (const float*)d_in[3];
  const float* b_Wa = (const float*)d_in[4];
  const float* U_a  = (const float*)d_in[5];
  const float* b_Ua = (const float*)d_in[6];
  const float* v_a  = (const float*)d_in[7];
  /* d_in[8] b_va: softmax-invariant, unused */
  const float* W_ih = (const float*)d_in[9];
  const float* b_ih = (const float*)d_in[10];
  const float* W_hh = (const float*)d_in[11];
  const float* b_hh = (const float*)d_in[12];
  const float* fc_W = (const float*)d_in[13];
  const float* fc_b = (const float*)d_in[14];
  const float* Wh   = (const float*)d_in[15];
  const float* bh   = (const float*)d_in[16];
  const float* Wc   = (const float*)d_in[17];
  const float* bc   = (const float*)d_in[18];

  char* ws = (char*)d_ws;
  size_t off = 0;
  auto alloc = [&](size_t bytes) { void* p = ws + off; off += (bytes + 255) & ~(size_t)255; return p; };
  f16* feat_h  = (f16*)alloc(6422528ull * 2);   // B*P*F
  f16* W_a_h   = (f16*)alloc(1048576ull * 2);   // H*F
  f16* W_ih_h  = (f16*)alloc(5242880ull * 2);   // 4H*(E+F)
  f16* fc_W_h  = (f16*)alloc(16384000ull * 2);  // V*H
  f16* Aemb    = (f16*)alloc(1048576ull * 2);   // B*S*E
  f16* Wcat_h  = (f16*)alloc(1310720ull * 2);   // [W_hh;U_a] = [2560,512] f16
  f16* Whc_h   = (f16*)alloc(2097152ull * 2);   // [Wh;Wc] = [1024,2048] f16
  f16* mean_h  = (f16*)alloc(131072ull * 2);    // [64,2048] mean features f16
  f16* att1_h  = (f16*)alloc(1605632ull * 2);   // B*P*H
  f16* featW4  = (f16*)alloc(6422528ull * 2);   // B*P*4H interleaved
  float* gates_x = (float*)alloc(4194304ull * 4); // B*S*4H
  float* R     = (float*)alloc(163840ull * 4);  // [64,2560] per-step GEMM out (also h0/c0 out)
  f16* h16     = (f16*)alloc(32768ull * 2);     // [64,512] h state
  float* c_state = (float*)alloc(32768ull * 4); // [64,512] c state
  f16* Hbuf    = (f16*)alloc(1048576ull * 2);   // B*S*H
  (void)ws_size; (void)in_sizes; (void)n_in; (void)out_size;

  float* out_logits = (float*)d_out;
  float* out_attw   = out_logits + 65536000ull;

  // Phase A: converts / packs / precompute
  k_cvt<<<2048, 256, 0, stream>>>(feat, feat_h, 6422528 / 4);
  k_cvt<<<1024, 256, 0, stream>>>(W_a, W_a_h, 1048576 / 4);
  k_cvt<<<2048, 256, 0, stream>>>(W_ih, W_ih_h, 5242880 / 4);
  k_cvt<<<4096, 256, 0, stream>>>(fc_W, fc_W_h, 16384000 / 4);
  k_cvt<<<1024, 256, 0, stream>>>(W_hh, Wcat_h, 1048576 / 4);              // rows 0..2047
  k_cvt<<<256, 256, 0, stream>>>(U_a, Wcat_h + 2048ull * 512, 262144 / 4); // rows 2048..2559
  k_cvt<<<512, 256, 0, stream>>>(Wh, Whc_h, 1048576 / 4);                  // rows 0..511
  k_cvt<<<512, 256, 0, stream>>>(Wc, Whc_h + 1048576ull, 1048576 / 4);     // rows 512..1023
  k_embed<<<2048, 256, 0, stream>>>(caps, etab, Aemb);
  k_mean<<<dim3(64, 2), 256, 0, stream>>>(feat_h, mean_h);

  dim3 blk(256);
  // h0/c0: [64,1024] = mean_h @ [Wh;Wc]^T  K=2048 -> f32 (biases added in split)
  k_gemm<<<16, blk, 0, stream>>>(mean_h, 2048, Whc_h, 2048,
                                 nullptr, nullptr, R, 1024, 2048, 0, 1);
  k_h0split<<<64, 512, 0, stream>>>(R, bh, bc, h16, c_state);

  // att1 = features @ W_a^T + b_Wa         [3136,512]  K=2048 -> f16   (49 m x 8 n)
  k_gemm<<<49 * 8, blk, 0, stream>>>(feat_h, 2048, W_a_h, 2048,
                                     b_Wa, nullptr, att1_h, 512, 2048, 1, 49);
  // featW = features @ W_ih[:,E:]^T        [3136,2048] K=2048 -> f16 g-interleaved (49 x 32)
  k_gemm<<<49 * 32, blk, 0, stream>>>(feat_h, 2048, W_ih_h + 512, 2560,
                                      nullptr, nullptr, featW4, 0, 2048, 2, 49);
  // gates_x = embed @ W_ih[:,:E]^T + b_ih + b_hh   [2048,2048] K=512 -> f32 (16 x 16 @128)
  k_gemm128<<<16 * 16, 512, 0, stream>>>(Aemb, 512, W_ih_h, 2560,
                                         b_ih, b_hh, gates_x, 2048, 512, 16);

  // Phase B: sequential recurrence — per step: register-MFMA GEMM + fused step kernel
  for (int t = 0; t < 32; ++t) {
    k_rgemm<<<40, blk, 0, stream>>>(h16, Wcat_h, R);
    k_step<<<64, 512, 0, stream>>>(R, b_Ua, att1_h, v_a, featW4, gates_x,
                                   c_state, h16, Hbuf, out_attw, t);
  }

  // Phase C: logits = H @ fc_W^T + fc_b    [2048,32000] K=512 -> f32 (16 m x 250 n @128)
  k_gemm128<<<16 * 250, 512, 0, stream>>>(Hbuf, 512, fc_W_h, 512,
                                          fc_b, nullptr, out_logits, 32000, 512, 16);
}